// Round 1
// 1055.316 us; speedup vs baseline: 2.3589x; 2.3589x over previous
//
#include <hip/hip_runtime.h>
#include <math.h>

// BiDAF attention, MFMA rewrite.
// B=64, T=2048, J=256, D=200. Output g: (B,T,4D).
//
//  k_cterm : cterm[b][j] = dot(u[b,j], w_u) + (b_h+b_u+b_hu)       (unchanged)
//  k_main  : per (b, 64-row t-tile), 4 waves x 16 rows.
//            s = (h.w_hu) @ u^T via v_mfma_f32_16x16x32_bf16 with hi/lo
//            bf16 split (3 cross terms -> ~fp32 accuracy), flash online
//            softmax over 8 j-chunks of 32, PV (c2q) also split-MFMA.
//            Writes g[:,0:D]=h, g[:,D:2D]=c2q, g[:,2D:3D]=h*c2q, m[b][t].
//  k_stats : per b: M=max_t m, iZ=1/sum exp(m-M)                    (unchanged)
//  k_q2c   : q2c[b][d] = sum_t exp(m-M)*iZ * h[b,t,d]               (unchanged)
//  k_g3    : g[:, 3D:4D] = h * q2c[b]                               (unchanged)

#define B_ 64
#define T_ 2048
#define J_ 256
#define D_ 200
#define DP 224      // D padded to 7*32 for MFMA K-steps
#define TM 64       // t-rows per k_main block
#define JC 32       // j-chunk
#define NCH (J_ / JC)
#define XS 232      // row stride (ushort) for [t][d]/[j][d] bf16 tiles: 464B, 16B-aligned, 2-way banks
#define TS 40       // row stride (ushort) for transposed [d][j] tiles: 80B, 16B-aligned
#define PS 40       // row stride (ushort) for P tiles
#define CQS 228     // row stride (float) for c2q scratch: 912B, 16B-aligned

typedef __attribute__((ext_vector_type(8))) short bf16x8;
typedef __attribute__((ext_vector_type(4))) float f32x4;

__device__ __forceinline__ ushort bf_hi(float v) {
  const unsigned uu = __float_as_uint(v);
  return (ushort)((uu + 0x7FFFu + ((uu >> 16) & 1u)) >> 16);  // RTNE bf16
}
__device__ __forceinline__ float bf_f(ushort hh) {
  return __uint_as_float(((unsigned)hh) << 16);
}

__global__ __launch_bounds__(256) void k_cterm(
    const float* __restrict__ u, const float* __restrict__ w_u,
    const float* __restrict__ b_h, const float* __restrict__ b_u,
    const float* __restrict__ b_hu, float* __restrict__ cterm) {
  const int wave = (blockIdx.x * 256 + threadIdx.x) >> 6;  // one wave per (b,j) row
  const int lane = threadIdx.x & 63;
  if (wave >= B_ * J_) return;
  const float* row = u + (size_t)wave * D_;
  float p = 0.f;
  for (int d = lane; d < D_; d += 64) p += row[d] * w_u[d];
  for (int off = 32; off > 0; off >>= 1) p += __shfl_xor(p, off, 64);
  if (lane == 0) cterm[wave] = p + b_h[0] + b_u[0] + b_hu[0];
}

__global__ __launch_bounds__(256, 1) void k_main(
    const float* __restrict__ h, const float* __restrict__ u,
    const float* __restrict__ w_h, const float* __restrict__ w_hu,
    const float* __restrict__ cterm, float* __restrict__ g,
    float* __restrict__ m_out) {
  __shared__ __align__(16) ushort xbuf[2][TM][XS];   // X=h*w_hu hi/lo; cq overlay at epilogue
  __shared__ __align__(16) ushort ubuf[2][JC][XS];   // U chunk hi/lo, [j][d]
  __shared__ __align__(16) ushort utb[2][DP][TS];    // U chunk hi/lo, transposed [d][j]
  __shared__ __align__(16) ushort pbuf[2][TM][PS];   // P hi/lo, [t][j]
  __shared__ float ctl[J_];
  __shared__ float rtl[TM];

  const int tid = threadIdx.x;
  const int b = blockIdx.y;
  const int t0 = blockIdx.x * TM;
  const int w = tid >> 6;     // wave 0..3 -> t-rows [w*16, w*16+16)
  const int l = tid & 63;
  const int c = l & 15;       // MFMA col-lane / frag-row lane
  const int gq = l >> 4;      // MFMA group 0..3
  const int w16 = w * 16;

  // ---- zero pads (d in [200,224) must be 0 for the MFMA K-loop) ----
  for (int i = tid; i < TM * 32; i += 256) {
    const int r = i >> 5, cc = 200 + (i & 31);
    xbuf[0][r][cc] = 0; xbuf[1][r][cc] = 0;
  }
  for (int i = tid; i < JC * 32; i += 256) {
    const int r = i >> 5, cc = 200 + (i & 31);
    ubuf[0][r][cc] = 0; ubuf[1][r][cc] = 0;
  }
  for (int i = tid; i < 24 * TS; i += 256) {
    const int r = 200 + i / TS, cc = i % TS;
    utb[0][r][cc] = 0; utb[1][r][cc] = 0;
  }
  // ---- stage X = h * w_hu, hi/lo bf16 split ----
  for (int i = tid; i < TM * 50; i += 256) {
    const int r = i / 50, c4 = (i % 50) * 4;
    const float4 hv = *(const float4*)(h + ((size_t)(b * T_ + t0 + r)) * D_ + c4);
    const float4 wv = *(const float4*)(w_hu + c4);
    const float x0 = hv.x * wv.x, x1 = hv.y * wv.y, x2 = hv.z * wv.z, x3 = hv.w * wv.w;
    const ushort h0 = bf_hi(x0), h1 = bf_hi(x1), h2 = bf_hi(x2), h3 = bf_hi(x3);
    *(ushort4*)&xbuf[0][r][c4] = make_ushort4(h0, h1, h2, h3);
    *(ushort4*)&xbuf[1][r][c4] = make_ushort4(
        bf_hi(x0 - bf_f(h0)), bf_hi(x1 - bf_f(h1)),
        bf_hi(x2 - bf_f(h2)), bf_hi(x3 - bf_f(h3)));
  }
  ctl[tid] = cterm[b * J_ + tid];
  // ---- rt[t] = dot(h[t], w_h) fp32, 4 lanes per row ----
  {
    const int r = tid >> 2, q = tid & 3;
    const float* hr = h + ((size_t)(b * T_ + t0 + r)) * D_;
    float p = 0.f;
    for (int d = q; d < D_; d += 4) p = fmaf(hr[d], w_h[d], p);
    p += __shfl_xor(p, 1, 4);
    p += __shfl_xor(p, 2, 4);
    if (q == 0) rtl[r] = p;
  }
  __syncthreads();

  float m_run[4] = {-INFINITY, -INFINITY, -INFINITY, -INFINITY};
  float l_run[4] = {0.f, 0.f, 0.f, 0.f};
  const f32x4 zz = {0.f, 0.f, 0.f, 0.f};
  f32x4 cacc[14];
#pragma unroll
  for (int dt = 0; dt < 14; ++dt) cacc[dt] = zz;

#pragma unroll 1
  for (int ch = 0; ch < NCH; ++ch) {
    const int j0 = ch * JC;
    // ---- stage U chunk: hi/lo in [j][d] and transposed [d][j] ----
    const float* ub = u + ((size_t)(b * J_ + j0)) * D_;
    for (int i = tid; i < JC * 50; i += 256) {
      const int r = i / 50, c4 = (i % 50) * 4;
      const float4 uv = *(const float4*)(ub + (size_t)r * D_ + c4);
      const ushort h0 = bf_hi(uv.x), h1 = bf_hi(uv.y), h2 = bf_hi(uv.z), h3 = bf_hi(uv.w);
      const ushort q0 = bf_hi(uv.x - bf_f(h0)), q1 = bf_hi(uv.y - bf_f(h1)),
                   q2 = bf_hi(uv.z - bf_f(h2)), q3 = bf_hi(uv.w - bf_f(h3));
      *(ushort4*)&ubuf[0][r][c4] = make_ushort4(h0, h1, h2, h3);
      *(ushort4*)&ubuf[1][r][c4] = make_ushort4(q0, q1, q2, q3);
      utb[0][c4 + 0][r] = h0; utb[0][c4 + 1][r] = h1;
      utb[0][c4 + 2][r] = h2; utb[0][c4 + 3][r] = h3;
      utb[1][c4 + 0][r] = q0; utb[1][c4 + 1][r] = q1;
      utb[1][c4 + 2][r] = q2; utb[1][c4 + 3][r] = q3;
    }
    __syncthreads();

    // ---- s = X @ U^T, 3-term split: Xh*Uh + Xl*Uh + Xh*Ul ----
    f32x4 s_hh0 = zz, s_lh0 = zz, s_hl0 = zz, s_hh1 = zz, s_lh1 = zz, s_hl1 = zz;
#pragma unroll
    for (int ks = 0; ks < 7; ++ks) {
      const int k0 = ks * 32 + gq * 8;
      const bf16x8 ah  = *(const bf16x8*)&xbuf[0][w16 + c][k0];
      const bf16x8 al  = *(const bf16x8*)&xbuf[1][w16 + c][k0];
      const bf16x8 b0h = *(const bf16x8*)&ubuf[0][c][k0];
      const bf16x8 b0l = *(const bf16x8*)&ubuf[1][c][k0];
      const bf16x8 b1h = *(const bf16x8*)&ubuf[0][16 + c][k0];
      const bf16x8 b1l = *(const bf16x8*)&ubuf[1][16 + c][k0];
      s_hh0 = __builtin_amdgcn_mfma_f32_16x16x32_bf16(ah, b0h, s_hh0, 0, 0, 0);
      s_lh0 = __builtin_amdgcn_mfma_f32_16x16x32_bf16(al, b0h, s_lh0, 0, 0, 0);
      s_hl0 = __builtin_amdgcn_mfma_f32_16x16x32_bf16(ah, b0l, s_hl0, 0, 0, 0);
      s_hh1 = __builtin_amdgcn_mfma_f32_16x16x32_bf16(ah, b1h, s_hh1, 0, 0, 0);
      s_lh1 = __builtin_amdgcn_mfma_f32_16x16x32_bf16(al, b1h, s_lh1, 0, 0, 0);
      s_hl1 = __builtin_amdgcn_mfma_f32_16x16x32_bf16(ah, b1l, s_hl1, 0, 0, 0);
    }

    // ---- online softmax (C layout: col=lane&15=j, row=gq*4+r=t) ----
    const float ct0 = ctl[j0 + c];
    const float ct1 = ctl[j0 + 16 + c];
    float a_r[4];
#pragma unroll
    for (int r = 0; r < 4; ++r) {
      const float rt_t = rtl[w16 + gq * 4 + r];
      const float s0 = ((s_hh0[r] + s_lh0[r]) + s_hl0[r]) + rt_t + ct0;
      const float s1 = ((s_hh1[r] + s_lh1[r]) + s_hl1[r]) + rt_t + ct1;
      float mx = fmaxf(s0, s1);
      mx = fmaxf(mx, __shfl_xor(mx, 8, 16));
      mx = fmaxf(mx, __shfl_xor(mx, 4, 16));
      mx = fmaxf(mx, __shfl_xor(mx, 2, 16));
      mx = fmaxf(mx, __shfl_xor(mx, 1, 16));
      const float mnew = fmaxf(m_run[r], mx);
      const float a = __expf(m_run[r] - mnew);  // first chunk: exp(-inf)=0
      const float p0 = __expf(s0 - mnew);
      const float p1 = __expf(s1 - mnew);
      float ps = p0 + p1;
      ps += __shfl_xor(ps, 8, 16);
      ps += __shfl_xor(ps, 4, 16);
      ps += __shfl_xor(ps, 2, 16);
      ps += __shfl_xor(ps, 1, 16);
      l_run[r] = l_run[r] * a + ps;
      m_run[r] = mnew;
      a_r[r] = a;
      const int pr = w16 + gq * 4 + r;
      const ushort p0h = bf_hi(p0), p1h = bf_hi(p1);
      pbuf[0][pr][c] = p0h;
      pbuf[0][pr][16 + c] = p1h;
      pbuf[1][pr][c] = bf_hi(p0 - bf_f(p0h));
      pbuf[1][pr][16 + c] = bf_hi(p1 - bf_f(p1h));
    }
    const f32x4 av = {a_r[0], a_r[1], a_r[2], a_r[3]};
#pragma unroll
    for (int dt = 0; dt < 14; ++dt) cacc[dt] *= av;

    // ---- PV: c2q += P @ U (Ph*Uh + Pl*Uh + Ph*Ul); P only crosses lanes
    //      within this wave, so no barrier needed before the reads. ----
    const bf16x8 pah = *(const bf16x8*)&pbuf[0][w16 + c][gq * 8];
    const bf16x8 pal = *(const bf16x8*)&pbuf[1][w16 + c][gq * 8];
#pragma unroll
    for (int dt = 0; dt < 14; ++dt) {
      const bf16x8 bh = *(const bf16x8*)&utb[0][dt * 16 + c][gq * 8];
      const bf16x8 bl = *(const bf16x8*)&utb[1][dt * 16 + c][gq * 8];
      cacc[dt] = __builtin_amdgcn_mfma_f32_16x16x32_bf16(pah, bh, cacc[dt], 0, 0, 0);
      cacc[dt] = __builtin_amdgcn_mfma_f32_16x16x32_bf16(pal, bh, cacc[dt], 0, 0, 0);
      cacc[dt] = __builtin_amdgcn_mfma_f32_16x16x32_bf16(pah, bl, cacc[dt], 0, 0, 0);
    }
    __syncthreads();  // protect next chunk's staging from this chunk's readers
  }

  // ---- epilogue ----
  if (c == 0) {
#pragma unroll
    for (int r = 0; r < 4; ++r) m_out[b * T_ + t0 + w16 + gq * 4 + r] = m_run[r];
  }
  const f32x4 invv = {1.f / l_run[0], 1.f / l_run[1], 1.f / l_run[2], 1.f / l_run[3]};
  float* cq = (float*)&xbuf[0][0][0];  // 64*228*4 = 58368 <= sizeof(xbuf) = 59392
#pragma unroll
  for (int dt = 0; dt < 14; ++dt) {
    const f32x4 cv = cacc[dt] * invv;
    const int d = dt * 16 + c;
    cq[(w16 + gq * 4 + 0) * CQS + d] = cv[0];
    cq[(w16 + gq * 4 + 1) * CQS + d] = cv[1];
    cq[(w16 + gq * 4 + 2) * CQS + d] = cv[2];
    cq[(w16 + gq * 4 + 3) * CQS + d] = cv[3];
  }
  __syncthreads();
  for (int i = tid; i < TM * 50; i += 256) {
    const int r = i / 50, c4 = (i % 50) * 4;
    const size_t row = (size_t)(b * T_ + t0 + r);
    const float4 hv = *(const float4*)(h + row * D_ + c4);
    const float4 cv = *(const float4*)(cq + r * CQS + c4);
    float* gb = g + row * (4 * D_);
    *(float4*)(gb + c4) = hv;
    *(float4*)(gb + D_ + c4) = cv;
    *(float4*)(gb + 2 * D_ + c4) =
        make_float4(hv.x * cv.x, hv.y * cv.y, hv.z * cv.z, hv.w * cv.w);
  }
}

__global__ __launch_bounds__(256) void k_stats(
    const float* __restrict__ m, float* __restrict__ Mb, float* __restrict__ iZb) {
  const int b = blockIdx.x, tid = threadIdx.x;
  __shared__ float redm[4], reds[4];
  const float* mb = m + b * T_;
  float mx = -INFINITY;
  for (int tt = tid; tt < T_; tt += 256) mx = fmaxf(mx, mb[tt]);
  for (int off = 32; off > 0; off >>= 1) mx = fmaxf(mx, __shfl_xor(mx, off, 64));
  if ((tid & 63) == 0) redm[tid >> 6] = mx;
  __syncthreads();
  const float M = fmaxf(fmaxf(redm[0], redm[1]), fmaxf(redm[2], redm[3]));
  float se = 0.f;
  for (int tt = tid; tt < T_; tt += 256) se += __expf(mb[tt] - M);
  for (int off = 32; off > 0; off >>= 1) se += __shfl_xor(se, off, 64);
  if ((tid & 63) == 0) reds[tid >> 6] = se;
  __syncthreads();
  if (tid == 0) {
    Mb[b] = M;
    iZb[b] = 1.f / (reds[0] + reds[1] + reds[2] + reds[3]);
  }
}

__global__ __launch_bounds__(256) void k_q2c(
    const float* __restrict__ h, const float* __restrict__ m,
    const float* __restrict__ Mb, const float* __restrict__ iZb,
    float* __restrict__ q2c) {
  const int b = blockIdx.y;
  const int t0 = blockIdx.x * 32;
  const int tid = threadIdx.x;
  __shared__ float wl[32];
  if (tid < 32) wl[tid] = __expf(m[b * T_ + t0 + tid] - Mb[b]) * iZb[b];
  __syncthreads();
  if (tid < D_) {
    float acc = 0.f;
    const float* hb = h + ((size_t)(b * T_ + t0)) * D_ + tid;
    for (int tt = 0; tt < 32; ++tt) acc = fmaf(wl[tt], hb[(size_t)tt * D_], acc);
    atomicAdd(&q2c[b * D_ + tid], acc);
  }
}

__global__ __launch_bounds__(256) void k_g3(
    const float* __restrict__ h, const float* __restrict__ q2c,
    float* __restrict__ g) {
  const unsigned i = blockIdx.x * 256u + threadIdx.x;
  if (i >= (unsigned)(B_ * T_ * D_)) return;
  const unsigned row = i / D_;       // b*T + t
  const unsigned d = i - row * D_;
  const unsigned b = row >> 11;      // T_ = 2048
  g[(size_t)row * (4 * D_) + 3 * D_ + d] = h[i] * q2c[b * D_ + d];
}

extern "C" void kernel_launch(void* const* d_in, const int* in_sizes, int n_in,
                              void* d_out, int out_size, void* d_ws, size_t ws_size,
                              hipStream_t stream) {
  const float* h    = (const float*)d_in[0];
  const float* u    = (const float*)d_in[1];
  const float* w_h  = (const float*)d_in[2];
  const float* b_h  = (const float*)d_in[3];
  const float* w_u  = (const float*)d_in[4];
  const float* b_u  = (const float*)d_in[5];
  const float* w_hu = (const float*)d_in[6];
  const float* b_hu = (const float*)d_in[7];
  float* g = (float*)d_out;

  float* ws    = (float*)d_ws;
  float* cterm = ws;                       // B*J      = 16384
  float* m     = ws + 16384;               // B*T      = 131072
  float* Mb    = ws + 16384 + 131072;      // B        = 64
  float* iZb   = Mb + 64;                  // B        = 64
  float* q2c   = iZb + 64;                 // B*D      = 12800

  hipMemsetAsync(q2c, 0, (size_t)B_ * D_ * sizeof(float), stream);

  k_cterm<<<(B_ * J_) / 4, 256, 0, stream>>>(u, w_u, b_h, b_u, b_hu, cterm);
  k_main<<<dim3(T_ / TM, B_), 256, 0, stream>>>(h, u, w_h, w_hu, cterm, g, m);
  k_stats<<<B_, 256, 0, stream>>>(m, Mb, iZb);
  k_q2c<<<dim3(T_ / 32, B_), 256, 0, stream>>>(h, m, Mb, iZb, q2c);
  k_g3<<<(B_ * T_ * D_ + 255) / 256, 256, 0, stream>>>(h, q2c, g);
}

// Round 2
// 868.534 us; speedup vs baseline: 2.8661x; 1.2151x over previous
//
#include <hip/hip_runtime.h>
#include <math.h>

// BiDAF attention, MFMA + conflict-free LDS + 2-block occupancy.
// B=64, T=2048, J=256, D=200. Output g: (B,T,4D).
//
//  k_cterm : cterm[b][j] = dot(u[b,j], w_u) + (b_h+b_u+b_hu)
//  k_main  : per (b, 64-row t-tile), 4 waves x 16 rows.
//            X = h*w_hu hi/lo bf16 A-frags held in REGISTERS (56 VGPR).
//            s = X @ u^T via v_mfma_f32_16x16x32_bf16 (3-term hi/lo split),
//            flash softmax over 8 j-chunks of 32, PV split-MFMA.
//            U^T tile staged with along-j ushort4 writes + 16B-block XOR
//            swizzle (conflict-free); pbuf same swizzle trick.
//            LDS 74.5KB -> 2 blocks/CU (launch_bounds(256,2)).
//  k_stats : per b: M=max_t m, iZ=1/sum exp(m-M)
//  k_q2c   : q2c[b][d] = sum_t exp(m-M)*iZ * h[b,t,d]   (atomic partials)
//  k_g3    : g[:, 3D:4D] = h * q2c[b]   (grid-stride float4)

#define B_ 64
#define T_ 2048
#define J_ 256
#define D_ 200
#define TM 64      // t-rows per k_main block
#define JC 32      // j-chunk
#define NCH (J_ / JC)
#define XS 232     // ubuf row stride (ushort): 464B -> 2-way banks on b128 reads (free)
#define TS 40      // utb row stride (ushort): 80B, swizzled 16B blocks
#define PS 40      // pbuf row stride (ushort)
#define UTR 208    // utb rows: 200 + 8 zero pad (PV covers d<208)
#define NDT 13     // PV d-tiles: 13*16 = 208
#define CQS 212    // cq scratch row stride (floats), 848B = 16B-aligned

typedef __attribute__((ext_vector_type(8))) short bf16x8;
typedef __attribute__((ext_vector_type(4))) float f32x4;

__device__ __forceinline__ ushort bf_hi(float v) {
  const unsigned uu = __float_as_uint(v);
  return (ushort)((uu + 0x7FFFu + ((uu >> 16) & 1u)) >> 16);  // RTNE bf16
}
__device__ __forceinline__ float bf_f(ushort hh) {
  return __uint_as_float(((unsigned)hh) << 16);
}

__global__ __launch_bounds__(256) void k_cterm(
    const float* __restrict__ u, const float* __restrict__ w_u,
    const float* __restrict__ b_h, const float* __restrict__ b_u,
    const float* __restrict__ b_hu, float* __restrict__ cterm) {
  const int wave = (blockIdx.x * 256 + threadIdx.x) >> 6;  // one wave per (b,j) row
  const int lane = threadIdx.x & 63;
  if (wave >= B_ * J_) return;
  const float* row = u + (size_t)wave * D_;
  float p = 0.f;
  for (int d = lane; d < D_; d += 64) p += row[d] * w_u[d];
  for (int off = 32; off > 0; off >>= 1) p += __shfl_xor(p, off, 64);
  if (lane == 0) cterm[wave] = p + b_h[0] + b_u[0] + b_hu[0];
}

__global__ __launch_bounds__(256, 2) void k_main(
    const float* __restrict__ h, const float* __restrict__ u,
    const float* __restrict__ w_h, const float* __restrict__ w_hu,
    const float* __restrict__ cterm, float* __restrict__ g,
    float* __restrict__ m_out) {
  __shared__ __align__(16) union SMem {
    struct {
      ushort ubuf[2][JC][XS];   // U chunk hi/lo, [j][d]         29696 B
      ushort utb[2][UTR][TS];   // U chunk hi/lo, [d][j] swz     33280 B
      ushort pbuf[2][TM][PS];   // P hi/lo, [t][j] swz           10240 B
      float ctl[J_];            //                                1024 B
      float rtl[TM];            //                                 256 B
    } s;                        // total 74496 B -> 2 blocks/CU
    float cq[TM][CQS];          // epilogue overlay (54272 B)
  } sm;

  const int tid = threadIdx.x;
  const int b = blockIdx.y;
  const int t0 = blockIdx.x * TM;
  const int w = tid >> 6;     // wave 0..3 -> t-rows [w*16, w*16+16)
  const int l = tid & 63;
  const int c = l & 15;       // MFMA row/col lane
  const int gq = l >> 4;      // MFMA k-group 0..3
  const int w16 = w * 16;

  // ---- zero pads ----
  for (int i = tid; i < JC * 32; i += 256) {       // ubuf cols 200..231
    const int r = i >> 5, cc = 200 + (i & 31);
    sm.s.ubuf[0][r][cc] = 0; sm.s.ubuf[1][r][cc] = 0;
  }
  for (int i = tid; i < 8 * TS; i += 256) {        // utb rows 200..207
    const int r = 200 + i / TS, cc = i % TS;
    sm.s.utb[0][r][cc] = 0; sm.s.utb[1][r][cc] = 0;
  }
  sm.s.ctl[tid] = cterm[b * J_ + tid];
  // ---- rt[t] = dot(h[t], w_h) fp32, 4 lanes per row ----
  {
    const int r = tid >> 2, q = tid & 3;
    const float* hr = h + ((size_t)(b * T_ + t0 + r)) * D_;
    float p = 0.f;
    for (int d = q; d < D_; d += 4) p = fmaf(hr[d], w_h[d], p);
    p += __shfl_xor(p, 1, 4);
    p += __shfl_xor(p, 2, 4);
    if (q == 0) sm.s.rtl[r] = p;
  }

  // ---- X = h*w_hu hi/lo A-frags in registers: lane needs X[w16+c][ks*32+gq*8..+7] ----
  bf16x8 xh[7], xl[7];
  {
    const float* hrow = h + ((size_t)(b * T_ + t0 + w16 + c)) * D_;
#pragma unroll
    for (int ks = 0; ks < 7; ++ks) {
      const int k0 = ks * 32 + gq * 8;
      bf16x8 vh = {0, 0, 0, 0, 0, 0, 0, 0};
      bf16x8 vl = {0, 0, 0, 0, 0, 0, 0, 0};
      if (k0 < 200) {  // ks<6 always; ks==6 only gq==0 (k0=192..199)
        const float4 a = *(const float4*)(hrow + k0);
        const float4 bq = *(const float4*)(hrow + k0 + 4);
        const float4 wa = *(const float4*)(w_hu + k0);
        const float4 wb = *(const float4*)(w_hu + k0 + 4);
        float xe[8] = {a.x * wa.x, a.y * wa.y, a.z * wa.z, a.w * wa.w,
                       bq.x * wb.x, bq.y * wb.y, bq.z * wb.z, bq.w * wb.w};
#pragma unroll
        for (int e = 0; e < 8; ++e) {
          const ushort hh = bf_hi(xe[e]);
          vh[e] = (short)hh;
          vl[e] = (short)bf_hi(xe[e] - bf_f(hh));
        }
      }
      xh[ks] = vh;
      xl[ks] = vl;
    }
  }
  __syncthreads();

  float m_run[4] = {-INFINITY, -INFINITY, -INFINITY, -INFINITY};
  float l_run[4] = {0.f, 0.f, 0.f, 0.f};
  const f32x4 zz = {0.f, 0.f, 0.f, 0.f};
  f32x4 cacc[NDT];
#pragma unroll
  for (int dt = 0; dt < NDT; ++dt) cacc[dt] = zz;

#pragma unroll 1
  for (int ch = 0; ch < NCH; ++ch) {
    const int j0 = ch * JC;
    const float* ub = u + ((size_t)(b * J_ + j0)) * D_;
    // ---- stage ubuf [j][d] hi/lo (coalesced along d) ----
    for (int i = tid; i < JC * 50; i += 256) {
      const int r = i / 50, c4 = (i - r * 50) * 4;
      const float4 uv = *(const float4*)(ub + (size_t)r * D_ + c4);
      const ushort h0 = bf_hi(uv.x), h1 = bf_hi(uv.y), h2 = bf_hi(uv.z), h3 = bf_hi(uv.w);
      *(ushort4*)&sm.s.ubuf[0][r][c4] = make_ushort4(h0, h1, h2, h3);
      *(ushort4*)&sm.s.ubuf[1][r][c4] = make_ushort4(
          bf_hi(uv.x - bf_f(h0)), bf_hi(uv.y - bf_f(h1)),
          bf_hi(uv.z - bf_f(h2)), bf_hi(uv.w - bf_f(h3)));
    }
    // ---- stage utb [d][j] swizzled: thread owns (d, 4 consecutive j) ----
    for (int i = tid; i < 8 * 200; i += 256) {
      const int j4 = i / 200, d = i - j4 * 200;  // lanes span consecutive d
      const float v0 = ub[(size_t)(j4 * 4 + 0) * D_ + d];
      const float v1 = ub[(size_t)(j4 * 4 + 1) * D_ + d];
      const float v2 = ub[(size_t)(j4 * 4 + 2) * D_ + d];
      const float v3 = ub[(size_t)(j4 * 4 + 3) * D_ + d];
      const ushort h0 = bf_hi(v0), h1 = bf_hi(v1), h2 = bf_hi(v2), h3 = bf_hi(v3);
      // 16B-block XOR swizzle: col = ((j>>3) ^ ((d>>3)&3))*8 + (j&7)
      const int off = (((j4 >> 1) ^ ((d >> 3) & 3)) << 3) + ((j4 & 1) << 2);
      *(ushort4*)&sm.s.utb[0][d][off] = make_ushort4(h0, h1, h2, h3);
      *(ushort4*)&sm.s.utb[1][d][off] = make_ushort4(
          bf_hi(v0 - bf_f(h0)), bf_hi(v1 - bf_f(h1)),
          bf_hi(v2 - bf_f(h2)), bf_hi(v3 - bf_f(h3)));
    }
    __syncthreads();

    // ---- s = X @ U^T, 3-term split: Xh*Uh + Xl*Uh + Xh*Ul ----
    f32x4 s_hh0 = zz, s_lh0 = zz, s_hl0 = zz, s_hh1 = zz, s_lh1 = zz, s_hl1 = zz;
#pragma unroll
    for (int ks = 0; ks < 7; ++ks) {
      const int k0 = ks * 32 + gq * 8;
      const bf16x8 b0h = *(const bf16x8*)&sm.s.ubuf[0][c][k0];
      const bf16x8 b0l = *(const bf16x8*)&sm.s.ubuf[1][c][k0];
      const bf16x8 b1h = *(const bf16x8*)&sm.s.ubuf[0][16 + c][k0];
      const bf16x8 b1l = *(const bf16x8*)&sm.s.ubuf[1][16 + c][k0];
      s_hh0 = __builtin_amdgcn_mfma_f32_16x16x32_bf16(xh[ks], b0h, s_hh0, 0, 0, 0);
      s_lh0 = __builtin_amdgcn_mfma_f32_16x16x32_bf16(xl[ks], b0h, s_lh0, 0, 0, 0);
      s_hl0 = __builtin_amdgcn_mfma_f32_16x16x32_bf16(xh[ks], b0l, s_hl0, 0, 0, 0);
      s_hh1 = __builtin_amdgcn_mfma_f32_16x16x32_bf16(xh[ks], b1h, s_hh1, 0, 0, 0);
      s_lh1 = __builtin_amdgcn_mfma_f32_16x16x32_bf16(xl[ks], b1h, s_lh1, 0, 0, 0);
      s_hl1 = __builtin_amdgcn_mfma_f32_16x16x32_bf16(xh[ks], b1l, s_hl1, 0, 0, 0);
    }

    // ---- online softmax (C layout: col=lane&15=j, row=gq*4+r=t) ----
    const float ct0 = sm.s.ctl[j0 + c];
    const float ct1 = sm.s.ctl[j0 + 16 + c];
    float a_r[4];
#pragma unroll
    for (int r = 0; r < 4; ++r) {
      const float rt_t = sm.s.rtl[w16 + gq * 4 + r];
      const float s0 = ((s_hh0[r] + s_lh0[r]) + s_hl0[r]) + rt_t + ct0;
      const float s1 = ((s_hh1[r] + s_lh1[r]) + s_hl1[r]) + rt_t + ct1;
      float mx = fmaxf(s0, s1);
      mx = fmaxf(mx, __shfl_xor(mx, 8, 16));
      mx = fmaxf(mx, __shfl_xor(mx, 4, 16));
      mx = fmaxf(mx, __shfl_xor(mx, 2, 16));
      mx = fmaxf(mx, __shfl_xor(mx, 1, 16));
      const float mnew = fmaxf(m_run[r], mx);
      const float a = __expf(m_run[r] - mnew);  // first chunk: exp(-inf)=0
      const float p0 = __expf(s0 - mnew);
      const float p1 = __expf(s1 - mnew);
      float ps = p0 + p1;
      ps += __shfl_xor(ps, 8, 16);
      ps += __shfl_xor(ps, 4, 16);
      ps += __shfl_xor(ps, 2, 16);
      ps += __shfl_xor(ps, 1, 16);
      l_run[r] = l_run[r] * a + ps;
      m_run[r] = mnew;
      a_r[r] = a;
      const int pr = w16 + gq * 4 + r;
      // pbuf swizzle: col = ((j>>3) ^ ((t>>2)&3))*8 + (j&7); (t>>2)&3 == gq here
      const ushort p0h = bf_hi(p0), p1h = bf_hi(p1);
      const int o0 = (((c >> 3) ^ gq) << 3) + (c & 7);
      const int o1 = ((((c >> 3) + 2) ^ gq) << 3) + (c & 7);
      sm.s.pbuf[0][pr][o0] = p0h;
      sm.s.pbuf[0][pr][o1] = p1h;
      sm.s.pbuf[1][pr][o0] = bf_hi(p0 - bf_f(p0h));
      sm.s.pbuf[1][pr][o1] = bf_hi(p1 - bf_f(p1h));
    }
    const f32x4 av = {a_r[0], a_r[1], a_r[2], a_r[3]};
#pragma unroll
    for (int dt = 0; dt < NDT; ++dt) cacc[dt] *= av;

    // ---- PV: c2q += P @ U (Ph*Uh + Pl*Uh + Ph*Ul); P is intra-wave ----
    const int psw = (gq ^ ((c >> 2) & 3)) << 3;   // pbuf read swizzle, row t=w16+c
    const bf16x8 pah = *(const bf16x8*)&sm.s.pbuf[0][w16 + c][psw];
    const bf16x8 pal = *(const bf16x8*)&sm.s.pbuf[1][w16 + c][psw];
#pragma unroll
    for (int dt = 0; dt < NDT; ++dt) {
      const int du = dt * 16 + c;
      const int osw = (gq ^ ((du >> 3) & 3)) << 3;  // utb read swizzle
      const bf16x8 bh = *(const bf16x8*)&sm.s.utb[0][du][osw];
      const bf16x8 bl = *(const bf16x8*)&sm.s.utb[1][du][osw];
      cacc[dt] = __builtin_amdgcn_mfma_f32_16x16x32_bf16(pah, bh, cacc[dt], 0, 0, 0);
      cacc[dt] = __builtin_amdgcn_mfma_f32_16x16x32_bf16(pal, bh, cacc[dt], 0, 0, 0);
      cacc[dt] = __builtin_amdgcn_mfma_f32_16x16x32_bf16(pah, bl, cacc[dt], 0, 0, 0);
    }
    __syncthreads();  // protect next chunk's staging from this chunk's readers
  }

  // ---- epilogue (cq overlays ubuf+utb; last loop-sync protects it) ----
  if (c == 0) {
#pragma unroll
    for (int r = 0; r < 4; ++r) m_out[b * T_ + t0 + w16 + gq * 4 + r] = m_run[r];
  }
  const f32x4 invv = {1.f / l_run[0], 1.f / l_run[1], 1.f / l_run[2], 1.f / l_run[3]};
#pragma unroll
  for (int dt = 0; dt < NDT; ++dt) {
    const f32x4 cv = cacc[dt] * invv;
    const int d = dt * 16 + c;
    sm.cq[w16 + gq * 4 + 0][d] = cv[0];
    sm.cq[w16 + gq * 4 + 1][d] = cv[1];
    sm.cq[w16 + gq * 4 + 2][d] = cv[2];
    sm.cq[w16 + gq * 4 + 3][d] = cv[3];
  }
  __syncthreads();
  for (int i = tid; i < TM * 50; i += 256) {
    const int r = i / 50, c4 = (i - r * 50) * 4;
    const size_t row = (size_t)(b * T_ + t0 + r);
    const float4 hv = *(const float4*)(h + row * D_ + c4);  // L1/L2-hot reload
    const float4 cv = *(const float4*)(&sm.cq[r][c4]);
    float* gb = g + row * (4 * D_);
    *(float4*)(gb + c4) = hv;
    *(float4*)(gb + D_ + c4) = cv;
    *(float4*)(gb + 2 * D_ + c4) =
        make_float4(hv.x * cv.x, hv.y * cv.y, hv.z * cv.z, hv.w * cv.w);
  }
}

__global__ __launch_bounds__(256) void k_stats(
    const float* __restrict__ m, float* __restrict__ Mb, float* __restrict__ iZb) {
  const int b = blockIdx.x, tid = threadIdx.x;
  __shared__ float redm[4], reds[4];
  const float* mb = m + b * T_;
  float mx = -INFINITY;
  for (int tt = tid; tt < T_; tt += 256) mx = fmaxf(mx, mb[tt]);
  for (int off = 32; off > 0; off >>= 1) mx = fmaxf(mx, __shfl_xor(mx, off, 64));
  if ((tid & 63) == 0) redm[tid >> 6] = mx;
  __syncthreads();
  const float M = fmaxf(fmaxf(redm[0], redm[1]), fmaxf(redm[2], redm[3]));
  float se = 0.f;
  for (int tt = tid; tt < T_; tt += 256) se += __expf(mb[tt] - M);
  for (int off = 32; off > 0; off >>= 1) se += __shfl_xor(se, off, 64);
  if ((tid & 63) == 0) reds[tid >> 6] = se;
  __syncthreads();
  if (tid == 0) {
    Mb[b] = M;
    iZb[b] = 1.f / (reds[0] + reds[1] + reds[2] + reds[3]);
  }
}

__global__ __launch_bounds__(256) void k_q2c(
    const float* __restrict__ h, const float* __restrict__ m,
    const float* __restrict__ Mb, const float* __restrict__ iZb,
    float* __restrict__ q2c) {
  const int b = blockIdx.y;
  const int t0 = blockIdx.x * 32;
  const int tid = threadIdx.x;
  __shared__ float wl[32];
  if (tid < 32) wl[tid] = __expf(m[b * T_ + t0 + tid] - Mb[b]) * iZb[b];
  __syncthreads();
  if (tid < D_) {
    float acc = 0.f;
    const float* hb = h + ((size_t)(b * T_ + t0)) * D_ + tid;
    for (int tt = 0; tt < 32; ++tt) acc = fmaf(wl[tt], hb[(size_t)tt * D_], acc);
    atomicAdd(&q2c[b * D_ + tid], acc);
  }
}

__global__ __launch_bounds__(256) void k_g3(
    const float* __restrict__ h, const float* __restrict__ q2c,
    float* __restrict__ g) {
  const int n4 = B_ * T_ * D_ / 4;  // 6,553,600 float4s
  for (int i = blockIdx.x * 256 + threadIdx.x; i < n4; i += gridDim.x * 256) {
    const int row = i / 50;          // 50 float4 per row
    const int d4 = i - row * 50;
    const int b = row >> 11;         // T_ = 2048
    const float4 hv = *(const float4*)(h + (size_t)i * 4);
    const float4 qv = *(const float4*)(q2c + b * D_ + d4 * 4);
    *(float4*)(g + (size_t)row * (4 * D_) + 3 * D_ + d4 * 4) =
        make_float4(hv.x * qv.x, hv.y * qv.y, hv.z * qv.z, hv.w * qv.w);
  }
}

extern "C" void kernel_launch(void* const* d_in, const int* in_sizes, int n_in,
                              void* d_out, int out_size, void* d_ws, size_t ws_size,
                              hipStream_t stream) {
  const float* h    = (const float*)d_in[0];
  const float* u    = (const float*)d_in[1];
  const float* w_h  = (const float*)d_in[2];
  const float* b_h  = (const float*)d_in[3];
  const float* w_u  = (const float*)d_in[4];
  const float* b_u  = (const float*)d_in[5];
  const float* w_hu = (const float*)d_in[6];
  const float* b_hu = (const float*)d_in[7];
  float* g = (float*)d_out;

  float* ws    = (float*)d_ws;
  float* cterm = ws;                       // B*J      = 16384
  float* m     = ws + 16384;               // B*T      = 131072
  float* Mb    = ws + 16384 + 131072;      // B        = 64
  float* iZb   = Mb + 64;                  // B        = 64
  float* q2c   = iZb + 64;                 // B*D      = 12800 (16B-aligned)

  hipMemsetAsync(q2c, 0, (size_t)B_ * D_ * sizeof(float), stream);

  k_cterm<<<(B_ * J_) / 4, 256, 0, stream>>>(u, w_u, b_h, b_u, b_hu, cterm);
  k_main<<<dim3(T_ / TM, B_), 256, 0, stream>>>(h, u, w_h, w_hu, cterm, g, m);
  k_stats<<<B_, 256, 0, stream>>>(m, Mb, iZb);
  k_q2c<<<dim3(T_ / 32, B_), 256, 0, stream>>>(h, m, Mb, iZb, q2c);
  k_g3<<<4096, 256, 0, stream>>>(h, q2c, g);
}